// Round 1
// baseline (1350.006 us; speedup 1.0000x reference)
//
#include <hip/hip_runtime.h>
#include <hip/hip_bf16.h>
#include <cmath>

#define T_TOK 8192
#define E_NUM 8
#define D_DIM 1024
#define H_DIM 4096

typedef __attribute__((ext_vector_type(4))) short bf16x4;
typedef __attribute__((ext_vector_type(8))) short bf16x8;
typedef __attribute__((ext_vector_type(4))) float f32x4;

__device__ __forceinline__ unsigned short f2bf(float f) {
  union { float f; unsigned u; } v; v.f = f;
  unsigned r = v.u + 0x7fffu + ((v.u >> 16) & 1u);
  return (unsigned short)(r >> 16);
}

// ---------------- convert x: fp32 -> bf16 ----------------
__global__ void __launch_bounds__(256) cvt_x_kernel(const float* __restrict__ x,
                                                    ushort* __restrict__ xb) {
  int i = blockIdx.x * 256 + threadIdx.x;
  float4 v = ((const float4*)x)[i];
  ushort4 o;
  o.x = f2bf(v.x); o.y = f2bf(v.y); o.z = f2bf(v.z); o.w = f2bf(v.w);
  ((ushort4*)xb)[i] = o;
}

// ------------- transpose + convert weights: [K][N] fp32 -> [N][K] bf16 -------------
__global__ void __launch_bounds__(256) transpose_cvt_kernel(
    const float* __restrict__ src, ushort* __restrict__ dst, int K, int N) {
  __shared__ float tile[32][33];
  size_t eoff = (size_t)blockIdx.z * K * N;
  src += eoff; dst += eoff;
  int n0 = blockIdx.x * 32, k0 = blockIdx.y * 32;
  int tx = threadIdx.x & 31, ty = threadIdx.x >> 5;  // 32 x 8
  for (int i = 0; i < 32; i += 8)
    tile[ty + i][tx] = src[(size_t)(k0 + ty + i) * N + n0 + tx];
  __syncthreads();
  for (int i = 0; i < 32; i += 8)
    dst[(size_t)(n0 + ty + i) * K + k0 + tx] = f2bf(tile[tx][ty + i]);
}

// ---------------- router: fp32, one wave per token ----------------
__global__ void __launch_bounds__(256) router_kernel(
    const float* __restrict__ x, const float* __restrict__ eps,
    const float* __restrict__ Wg, const float* __restrict__ bg,
    const float* __restrict__ Wn, const float* __restrict__ bn,
    int* __restrict__ tok, float* __restrict__ gateL, int* __restrict__ cnt) {
  int lane = threadIdx.x & 63;
  int t = blockIdx.x * 4 + (threadIdx.x >> 6);
  float ag[8], an[8];
#pragma unroll
  for (int e = 0; e < 8; ++e) { ag[e] = 0.f; an[e] = 0.f; }
  const float* xr = x + (size_t)t * D_DIM;
#pragma unroll 4
  for (int i = 0; i < 16; ++i) {
    int d = lane + i * 64;
    float xv = xr[d];
    const float4* g4 = (const float4*)(Wg + d * 8);
    const float4* n4 = (const float4*)(Wn + d * 8);
    float4 ga = g4[0], gb = g4[1], na = n4[0], nb = n4[1];
    ag[0] += xv * ga.x; ag[1] += xv * ga.y; ag[2] += xv * ga.z; ag[3] += xv * ga.w;
    ag[4] += xv * gb.x; ag[5] += xv * gb.y; ag[6] += xv * gb.z; ag[7] += xv * gb.w;
    an[0] += xv * na.x; an[1] += xv * na.y; an[2] += xv * na.z; an[3] += xv * na.w;
    an[4] += xv * nb.x; an[5] += xv * nb.y; an[6] += xv * nb.z; an[7] += xv * nb.w;
  }
#pragma unroll
  for (int off = 32; off > 0; off >>= 1) {
#pragma unroll
    for (int e = 0; e < 8; ++e) {
      ag[e] += __shfl_xor(ag[e], off);
      an[e] += __shfl_xor(an[e], off);
    }
  }
  if (lane == 0) {
    float noisy[8];
#pragma unroll
    for (int e = 0; e < 8; ++e) {
      float lg = ag[e] + bg[e];
      float ln = an[e] + bn[e];
      float sp = (ln > 20.f) ? ln : log1pf(expf(ln));
      noisy[e] = lg + eps[(size_t)t * 8 + e] * sp;
    }
    int i0 = 0; float v0 = noisy[0];
#pragma unroll
    for (int e = 1; e < 8; ++e) if (noisy[e] > v0) { v0 = noisy[e]; i0 = e; }
    int i1 = -1; float v1 = -1e30f;
#pragma unroll
    for (int e = 0; e < 8; ++e) if (e != i0 && noisy[e] > v1) { v1 = noisy[e]; i1 = e; }
    float ee = expf(v1 - v0);
    float g0 = 1.f / (1.f + ee);
    float g1 = ee / (1.f + ee);
    int p0 = atomicAdd(cnt + i0, 1);
    int p1 = atomicAdd(cnt + i1, 1);
    tok[i0 * T_TOK + p0] = t * 2;     gateL[i0 * T_TOK + p0] = g0;
    tok[i1 * T_TOK + p1] = t * 2 + 1; gateL[i1 * T_TOK + p1] = g1;
  }
}

// ---------------- gathered GEMM, 128x128 tile, BK=64, 4 waves ----------------
// FIRST=true : C = gelu(A@W1[e]+b1[e]) -> hbuf rows (bf16)
// FIRST=false: out[t] += gate * (A@W2[e]+b2[e])   (fp32 atomicAdd)
template <int KD, int NC, bool FIRST>
__global__ void __launch_bounds__(256) moe_gemm_kernel(
    const ushort* __restrict__ Abase, const ushort* __restrict__ Bt,
    const float* __restrict__ bias, const int* __restrict__ tok,
    const float* __restrict__ gateL, const int* __restrict__ cnt,
    ushort* __restrict__ hbuf, float* __restrict__ out) {
  int e = blockIdx.z;
  int c = cnt[e];
  int m0 = blockIdx.y * 128;
  if (m0 >= c) return;
  int n0 = blockIdx.x * 128;
  __shared__ __align__(16) ushort As[128][72];  // +8 bf16 pad: 16B-aligned rows, 2-way-max banks
  __shared__ __align__(16) ushort Bs[128][72];  // Bs[n][k]
  int tid = threadIdx.x;
  int lane = tid & 63, wave = tid >> 6;
  int wr = (wave >> 1) * 64, wc = (wave & 1) * 64;
  const int* tokE = tok + e * T_TOK;
  const ushort* Be = Bt + (size_t)e * NC * KD;

  const ushort* agp[4]; const ushort* bgp[4];
  ushort* alp[4]; ushort* blp[4];
#pragma unroll
  for (int s = 0; s < 4; ++s) {
    int idx = tid + s * 256;      // 0..1023
    int row = idx >> 3;           // 0..127
    int cg = (idx & 7) * 8;       // 0..56
    int p = m0 + row;
    int ar = 0;
    if (p < c) { int tsv = tokE[p]; ar = FIRST ? (tsv >> 1) : tsv; }
    agp[s] = Abase + (size_t)ar * KD + cg;
    bgp[s] = Be + (size_t)(n0 + row) * KD + cg;
    alp[s] = &As[row][cg];
    blp[s] = &Bs[row][cg];
  }

  f32x4 acc[4][4];
#pragma unroll
  for (int i = 0; i < 4; ++i)
#pragma unroll
    for (int j = 0; j < 4; ++j) {
      f32x4 z = {0.f, 0.f, 0.f, 0.f};
      acc[i][j] = z;
    }

  int r16 = lane & 15;
  int kh = (lane >> 4) << 2;

  for (int kt = 0; kt < KD / 64; ++kt) {
    __syncthreads();
#pragma unroll
    for (int s = 0; s < 4; ++s) {
      *(bf16x8*)alp[s] = *(const bf16x8*)(agp[s] + kt * 64);
      *(bf16x8*)blp[s] = *(const bf16x8*)(bgp[s] + kt * 64);
    }
    __syncthreads();
#pragma unroll
    for (int ks = 0; ks < 2; ++ks) {
      bf16x8 af[4], bfr[4];
#pragma unroll
      for (int i = 0; i < 4; ++i) {
        union { bf16x8 v8; bf16x4 v4[2]; } ua, ub;
        const ushort* ap = &As[wr + i * 16 + r16][ks * 32 + kh];
        ua.v4[0] = *(const bf16x4*)ap;
        ua.v4[1] = *(const bf16x4*)(ap + 16);
        af[i] = ua.v8;
        const ushort* bp = &Bs[wc + i * 16 + r16][ks * 32 + kh];
        ub.v4[0] = *(const bf16x4*)bp;
        ub.v4[1] = *(const bf16x4*)(bp + 16);
        bfr[i] = ub.v8;
      }
#pragma unroll
      for (int mi = 0; mi < 4; ++mi)
#pragma unroll
        for (int ni = 0; ni < 4; ++ni)
          acc[mi][ni] = __builtin_amdgcn_mfma_f32_16x16x32_bf16(
              af[mi], bfr[ni], acc[mi][ni], 0, 0, 0);
    }
  }

  const float* be = bias + (size_t)e * NC;
#pragma unroll
  for (int mi = 0; mi < 4; ++mi) {
#pragma unroll
    for (int r = 0; r < 4; ++r) {
      int rowl = wr + mi * 16 + ((lane >> 4) << 2) + r;
      int p = m0 + rowl;
      if (p < c) {
        int tsv = tokE[p];
        if (FIRST) {
          ushort* hrow = hbuf + (size_t)tsv * H_DIM;
#pragma unroll
          for (int ni = 0; ni < 4; ++ni) {
            int col = n0 + wc + ni * 16 + r16;
            float v = acc[mi][ni][r] + be[col];
            v = 0.5f * v * (1.f + erff(v * 0.70710678118654752f));
            hrow[col] = f2bf(v);
          }
        } else {
          float g = gateL[e * T_TOK + p];
          float* orow = out + (size_t)(tsv >> 1) * D_DIM;
#pragma unroll
          for (int ni = 0; ni < 4; ++ni) {
            int col = n0 + wc + ni * 16 + r16;
            float v = acc[mi][ni][r] + be[col];
            atomicAdd(&orow[col], g * v);
          }
        }
      }
    }
  }
}

extern "C" void kernel_launch(void* const* d_in, const int* in_sizes, int n_in,
                              void* d_out, int out_size, void* d_ws, size_t ws_size,
                              hipStream_t stream) {
  const float* x   = (const float*)d_in[0];
  const float* eps = (const float*)d_in[1];
  const float* Wg  = (const float*)d_in[2];
  const float* bg  = (const float*)d_in[3];
  const float* Wn  = (const float*)d_in[4];
  const float* bn  = (const float*)d_in[5];
  const float* W1  = (const float*)d_in[6];
  const float* b1  = (const float*)d_in[7];
  const float* W2  = (const float*)d_in[8];
  const float* b2  = (const float*)d_in[9];
  float* out = (float*)d_out;

  const size_t nXB = (size_t)T_TOK * D_DIM;
  const size_t nW1 = (size_t)E_NUM * D_DIM * H_DIM;
  const size_t nHB = (size_t)T_TOK * 2 * H_DIM;
  ushort* xb   = (ushort*)d_ws;
  ushort* W1T  = xb + nXB;            // [E][H][D] bf16 (n-major)
  ushort* W2T  = W1T + nW1;           // [E][D][H] bf16 (n-major)
  ushort* hbuf = W2T + nW1;           // [T*2][H] bf16
  int*   tok   = (int*)(hbuf + nHB);  // [E][T] token*2+slot
  float* gateL = (float*)(tok + E_NUM * T_TOK);
  int*   cnt   = (int*)(gateL + E_NUM * T_TOK);
  size_t need = (size_t)((char*)(cnt + 8) - (char*)d_ws);
  if (ws_size < need) return;  // insufficient scratch; avoid corruption

  hipMemsetAsync(cnt, 0, 8 * sizeof(int), stream);
  hipMemsetAsync(out, 0, (size_t)out_size * sizeof(float), stream);

  cvt_x_kernel<<<(int)(nXB / 4 / 256), 256, 0, stream>>>(x, xb);
  transpose_cvt_kernel<<<dim3(H_DIM / 32, D_DIM / 32, E_NUM), 256, 0, stream>>>(
      W1, W1T, D_DIM, H_DIM);
  transpose_cvt_kernel<<<dim3(D_DIM / 32, H_DIM / 32, E_NUM), 256, 0, stream>>>(
      W2, W2T, H_DIM, D_DIM);
  router_kernel<<<T_TOK / 4, 256, 0, stream>>>(x, eps, Wg, bg, Wn, bn, tok, gateL, cnt);
  moe_gemm_kernel<D_DIM, H_DIM, true>
      <<<dim3(H_DIM / 128, T_TOK / 128, E_NUM), 256, 0, stream>>>(
          xb, W1T, b1, tok, gateL, cnt, hbuf, out);
  moe_gemm_kernel<H_DIM, D_DIM, false>
      <<<dim3(D_DIM / 128, T_TOK / 128, E_NUM), 256, 0, stream>>>(
          hbuf, W2T, b2, tok, gateL, cnt, hbuf, out);
}

// Round 2
// 1131.258 us; speedup vs baseline: 1.1934x; 1.1934x over previous
//
#include <hip/hip_runtime.h>
#include <hip/hip_bf16.h>
#include <cmath>

#define T_TOK 8192
#define E_NUM 8
#define D_DIM 1024
#define H_DIM 4096

typedef __attribute__((ext_vector_type(4))) short bf16x4;
typedef __attribute__((ext_vector_type(8))) short bf16x8;
typedef __attribute__((ext_vector_type(4))) float f32x4;

__device__ __forceinline__ unsigned short f2bf(float f) {
  union { float f; unsigned u; } v; v.f = f;
  unsigned r = v.u + 0x7fffu + ((v.u >> 16) & 1u);
  return (unsigned short)(r >> 16);
}

__device__ __forceinline__ void gload_lds16(const void* g, void* l) {
  __builtin_amdgcn_global_load_lds(
      (const __attribute__((address_space(1))) unsigned int*)g,
      (__attribute__((address_space(3))) unsigned int*)l, 16, 0, 0);
}

// ---------------- convert x: fp32 -> bf16 ----------------
__global__ void __launch_bounds__(256) cvt_x_kernel(const float* __restrict__ x,
                                                    ushort* __restrict__ xb) {
  int i = blockIdx.x * 256 + threadIdx.x;
  float4 v = ((const float4*)x)[i];
  ushort4 o;
  o.x = f2bf(v.x); o.y = f2bf(v.y); o.z = f2bf(v.z); o.w = f2bf(v.w);
  ((ushort4*)xb)[i] = o;
}

// ------------- transpose + convert weights: [K][N] fp32 -> [N][K] bf16 -------------
__global__ void __launch_bounds__(256) transpose_cvt_kernel(
    const float* __restrict__ src, ushort* __restrict__ dst, int K, int N) {
  __shared__ float tile[32][33];
  size_t eoff = (size_t)blockIdx.z * K * N;
  src += eoff; dst += eoff;
  int n0 = blockIdx.x * 32, k0 = blockIdx.y * 32;
  int tx = threadIdx.x & 31, ty = threadIdx.x >> 5;  // 32 x 8
  for (int i = 0; i < 32; i += 8)
    tile[ty + i][tx] = src[(size_t)(k0 + ty + i) * N + n0 + tx];
  __syncthreads();
  for (int i = 0; i < 32; i += 8)
    dst[(size_t)(n0 + ty + i) * K + k0 + tx] = f2bf(tile[tx][ty + i]);
}

// ---------------- router: fp32, one wave per token ----------------
__global__ void __launch_bounds__(256) router_kernel(
    const float* __restrict__ x, const float* __restrict__ eps,
    const float* __restrict__ Wg, const float* __restrict__ bg,
    const float* __restrict__ Wn, const float* __restrict__ bn,
    int* __restrict__ tok, float* __restrict__ gateL, int* __restrict__ cnt) {
  int lane = threadIdx.x & 63;
  int t = blockIdx.x * 4 + (threadIdx.x >> 6);
  float ag[8], an[8];
#pragma unroll
  for (int e = 0; e < 8; ++e) { ag[e] = 0.f; an[e] = 0.f; }
  const float* xr = x + (size_t)t * D_DIM;
#pragma unroll 4
  for (int i = 0; i < 16; ++i) {
    int d = lane + i * 64;
    float xv = xr[d];
    const float4* g4 = (const float4*)(Wg + d * 8);
    const float4* n4 = (const float4*)(Wn + d * 8);
    float4 ga = g4[0], gb = g4[1], na = n4[0], nb = n4[1];
    ag[0] += xv * ga.x; ag[1] += xv * ga.y; ag[2] += xv * ga.z; ag[3] += xv * ga.w;
    ag[4] += xv * gb.x; ag[5] += xv * gb.y; ag[6] += xv * gb.z; ag[7] += xv * gb.w;
    an[0] += xv * na.x; an[1] += xv * na.y; an[2] += xv * na.z; an[3] += xv * na.w;
    an[4] += xv * nb.x; an[5] += xv * nb.y; an[6] += xv * nb.z; an[7] += xv * nb.w;
  }
#pragma unroll
  for (int off = 32; off > 0; off >>= 1) {
#pragma unroll
    for (int e = 0; e < 8; ++e) {
      ag[e] += __shfl_xor(ag[e], off);
      an[e] += __shfl_xor(an[e], off);
    }
  }
  if (lane == 0) {
    float noisy[8];
#pragma unroll
    for (int e = 0; e < 8; ++e) {
      float lg = ag[e] + bg[e];
      float ln = an[e] + bn[e];
      float sp = (ln > 20.f) ? ln : log1pf(expf(ln));
      noisy[e] = lg + eps[(size_t)t * 8 + e] * sp;
    }
    int i0 = 0; float v0 = noisy[0];
#pragma unroll
    for (int e = 1; e < 8; ++e) if (noisy[e] > v0) { v0 = noisy[e]; i0 = e; }
    int i1 = -1; float v1 = -1e30f;
#pragma unroll
    for (int e = 0; e < 8; ++e) if (e != i0 && noisy[e] > v1) { v1 = noisy[e]; i1 = e; }
    float ee = expf(v1 - v0);
    float g0 = 1.f / (1.f + ee);
    float g1 = ee / (1.f + ee);
    int p0 = atomicAdd(cnt + i0, 1);
    int p1 = atomicAdd(cnt + i1, 1);
    tok[i0 * T_TOK + p0] = t * 2;     gateL[i0 * T_TOK + p0] = g0;
    tok[i1 * T_TOK + p1] = t * 2 + 1; gateL[i1 * T_TOK + p1] = g1;
  }
}

// ---------------- gathered GEMM, m97 structure ----------------
// 128x128 tile, BK=64, 4 waves, global_load_lds(16B) into linear LDS,
// rule-#21 XOR swizzle (pre-swizzled global source + swizzled ds_read),
// XCD-chunked 1-D grid (m fastest => same-XCD blocks share a B panel).
// FIRST=true : C = gelu(A@W1[e]+b1[e]) -> hbuf rows (bf16)
// FIRST=false: out[t] += gate * (A@W2[e]+b2[e])   (fp32 atomicAdd)
template <int KD, int NC, bool FIRST>
__global__ void __launch_bounds__(256) moe_gemm_kernel(
    const ushort* __restrict__ Abase, const ushort* __restrict__ Bt,
    const float* __restrict__ bias, const int* __restrict__ tok,
    const float* __restrict__ gateL, const int* __restrict__ cnt,
    ushort* __restrict__ hbuf, float* __restrict__ out) {
  constexpr int MT = T_TOK / 128;
  constexpr int NT = NC / 128;
  // bijective XCD swizzle (nwg % 8 == 0 for both instantiations)
  int nwg = MT * NT * E_NUM;
  int q = nwg >> 3;
  int bid = blockIdx.x;
  int wg = (bid & 7) * q + (bid >> 3);
  int m_t = wg % MT;
  int n_t = (wg / MT) % NT;
  int e = wg / (MT * NT);

  int c = cnt[e];
  int m0 = m_t * 128;
  if (m0 >= c) return;
  int n0 = n_t * 128;

  __shared__ __align__(16) ushort As[128 * 64];  // linear, swizzled content
  __shared__ __align__(16) ushort Bs[128 * 64];
  int tid = threadIdx.x;
  int lane = tid & 63, wave = tid >> 6;
  int wr = (wave >> 1) * 64, wc = (wave & 1) * 64;
  const int* tokE = tok + e * T_TOK;
  const ushort* Be = Bt + (size_t)e * NC * KD;

  // staging sources: thread tid owns LDS 16B slot (row = p*32 + tid>>3, slot = tid&7)
  // global source column-slot is (slot ^ (row&7))  => LDS holds XOR-swizzled tile
  int srow = tid >> 3, scol = tid & 7;
  const ushort* asrc[4]; const ushort* bsrc[4];
#pragma unroll
  for (int p = 0; p < 4; ++p) {
    int r = p * 32 + srow;
    int pi = m0 + r;
    int ar = 0;
    if (pi < c) { int tsv = tokE[pi]; ar = FIRST ? (tsv >> 1) : tsv; }
    int sl = (scol ^ (r & 7)) * 8;  // element offset of swizzled 16B slot
    asrc[p] = Abase + (size_t)ar * KD + sl;
    bsrc[p] = Be + (size_t)(n0 + r) * KD + sl;
  }

  f32x4 acc[4][4];
#pragma unroll
  for (int i = 0; i < 4; ++i)
#pragma unroll
    for (int j = 0; j < 4; ++j) {
      f32x4 z = {0.f, 0.f, 0.f, 0.f};
      acc[i][j] = z;
    }

  int r16 = lane & 15;
  int kh8 = (lane >> 4) * 8;        // byte offset of this lane's k-chunk
  int swz = (r16 & 7) << 4;         // read-side XOR (row&7 == r16&7 for all frags)

  for (int kt = 0; kt < KD / 64; ++kt) {
    __syncthreads();
#pragma unroll
    for (int p = 0; p < 4; ++p)
      gload_lds16(asrc[p] + kt * 64, (char*)As + p * 4096 + tid * 16);
#pragma unroll
    for (int p = 0; p < 4; ++p)
      gload_lds16(bsrc[p] + kt * 64, (char*)Bs + p * 4096 + tid * 16);
    __syncthreads();  // compiler drains vmcnt(0) here (m97 structure)

#pragma unroll
    for (int ks = 0; ks < 2; ++ks) {
      bf16x8 af[4], bfr[4];
      int k0 = ks * 64 + kh8;
#pragma unroll
      for (int i = 0; i < 4; ++i) {
        int rowA = (wr + i * 16 + r16) * 128;
        union { bf16x8 v8; bf16x4 v4[2]; } ua, ub;
        ua.v4[0] = *(const bf16x4*)((const char*)As + rowA + (k0 ^ swz));
        ua.v4[1] = *(const bf16x4*)((const char*)As + rowA + ((k0 + 32) ^ swz));
        af[i] = ua.v8;
        int rowB = (wc + i * 16 + r16) * 128;
        ub.v4[0] = *(const bf16x4*)((const char*)Bs + rowB + (k0 ^ swz));
        ub.v4[1] = *(const bf16x4*)((const char*)Bs + rowB + ((k0 + 32) ^ swz));
        bfr[i] = ub.v8;
      }
#pragma unroll
      for (int mi = 0; mi < 4; ++mi)
#pragma unroll
        for (int ni = 0; ni < 4; ++ni)
          acc[mi][ni] = __builtin_amdgcn_mfma_f32_16x16x32_bf16(
              af[mi], bfr[ni], acc[mi][ni], 0, 0, 0);
    }
  }

  const float* be = bias + (size_t)e * NC;
#pragma unroll
  for (int mi = 0; mi < 4; ++mi) {
#pragma unroll
    for (int r = 0; r < 4; ++r) {
      int rowl = wr + mi * 16 + ((lane >> 4) << 2) + r;
      int p = m0 + rowl;
      if (p < c) {
        int tsv = tokE[p];
        if (FIRST) {
          ushort* hrow = hbuf + (size_t)tsv * H_DIM;
#pragma unroll
          for (int ni = 0; ni < 4; ++ni) {
            int col = n0 + wc + ni * 16 + r16;
            float v = acc[mi][ni][r] + be[col];
            v = 0.5f * v * (1.f + erff(v * 0.70710678118654752f));
            hrow[col] = f2bf(v);
          }
        } else {
          float g = gateL[e * T_TOK + p];
          float* orow = out + (size_t)(tsv >> 1) * D_DIM;
#pragma unroll
          for (int ni = 0; ni < 4; ++ni) {
            int col = n0 + wc + ni * 16 + r16;
            float v = acc[mi][ni][r] + be[col];
            atomicAdd(&orow[col], g * v);
          }
        }
      }
    }
  }
}

extern "C" void kernel_launch(void* const* d_in, const int* in_sizes, int n_in,
                              void* d_out, int out_size, void* d_ws, size_t ws_size,
                              hipStream_t stream) {
  const float* x   = (const float*)d_in[0];
  const float* eps = (const float*)d_in[1];
  const float* Wg  = (const float*)d_in[2];
  const float* bg  = (const float*)d_in[3];
  const float* Wn  = (const float*)d_in[4];
  const float* bn  = (const float*)d_in[5];
  const float* W1  = (const float*)d_in[6];
  const float* b1  = (const float*)d_in[7];
  const float* W2  = (const float*)d_in[8];
  const float* b2  = (const float*)d_in[9];
  float* out = (float*)d_out;

  const size_t nXB = (size_t)T_TOK * D_DIM;
  const size_t nW1 = (size_t)E_NUM * D_DIM * H_DIM;
  const size_t nHB = (size_t)T_TOK * 2 * H_DIM;
  ushort* xb   = (ushort*)d_ws;
  ushort* W1T  = xb + nXB;            // [E][H][D] bf16 (n-major)
  ushort* W2T  = W1T + nW1;           // [E][D][H] bf16 (n-major)
  ushort* hbuf = W2T + nW1;           // [T*2][H] bf16
  int*   tok   = (int*)(hbuf + nHB);  // [E][T] token*2+slot
  float* gateL = (float*)(tok + E_NUM * T_TOK);
  int*   cnt   = (int*)(gateL + E_NUM * T_TOK);
  size_t need = (size_t)((char*)(cnt + 8) - (char*)d_ws);
  if (ws_size < need) return;  // insufficient scratch; avoid corruption

  hipMemsetAsync(cnt, 0, 8 * sizeof(int), stream);
  hipMemsetAsync(out, 0, (size_t)out_size * sizeof(float), stream);

  cvt_x_kernel<<<(int)(nXB / 4 / 256), 256, 0, stream>>>(x, xb);
  transpose_cvt_kernel<<<dim3(H_DIM / 32, D_DIM / 32, E_NUM), 256, 0, stream>>>(
      W1, W1T, D_DIM, H_DIM);
  transpose_cvt_kernel<<<dim3(D_DIM / 32, H_DIM / 32, E_NUM), 256, 0, stream>>>(
      W2, W2T, H_DIM, D_DIM);
  router_kernel<<<T_TOK / 4, 256, 0, stream>>>(x, eps, Wg, bg, Wn, bn, tok, gateL, cnt);
  moe_gemm_kernel<D_DIM, H_DIM, true>
      <<<(T_TOK / 128) * (H_DIM / 128) * E_NUM, 256, 0, stream>>>(
          xb, W1T, b1, tok, gateL, cnt, hbuf, out);
  moe_gemm_kernel<H_DIM, D_DIM, false>
      <<<(T_TOK / 128) * (D_DIM / 128) * E_NUM, 256, 0, stream>>>(
          hbuf, W2T, b2, tok, gateL, cnt, hbuf, out);
}